// Round 2
// baseline (312.237 us; speedup 1.0000x reference)
//
#include <hip/hip_runtime.h>

typedef unsigned short u16;
typedef __bf16 bf16_t;
typedef bf16_t bf16x8 __attribute__((ext_vector_type(8)));
typedef float floatx4 __attribute__((ext_vector_type(4)));

static constexpr float kScale = 0.014731391274719741f;    // 1/sqrt(512*9)
static constexpr float kLinScale = 0.044194173824159216f; // 1/sqrt(512)

__device__ __forceinline__ u16 f2bf(float f) {
  unsigned u = __float_as_uint(f);
  u += 0x7FFFu + ((u >> 16) & 1u);
  return (u16)(u >> 16);
}

// async 16B global->LDS; LDS dst semantics: wave-uniform base + lane*16
#define GLD16(g, l)                                                        \
  __builtin_amdgcn_global_load_lds(                                        \
      (const __attribute__((address_space(1))) unsigned int*)(g),          \
      (__attribute__((address_space(3))) unsigned int*)(l), 16, 0, 0)

// ---------------------------------------------------------------------------
// s[b,c] = sum_s style[b,s]*modw[c,s]*lin_scale + bias[c]   (all f32)
__global__ __launch_bounds__(256) void k_style(const float* __restrict__ style,
                                               const float* __restrict__ modw,
                                               const float* __restrict__ modb,
                                               float* __restrict__ s_buf) {
  int tid = threadIdx.x, lane = tid & 63, wv = tid >> 6;
  int idx = blockIdx.x * 4 + wv; // [0,4096)
  int b = idx >> 9, c = idx & 511;
  const float* st = style + b * 512;
  const float* mw = modw + (size_t)c * 512;
  float s = 0.f;
#pragma unroll
  for (int i = 0; i < 8; ++i) s += st[lane + i * 64] * mw[lane + i * 64];
#pragma unroll
  for (int off = 32; off; off >>= 1) s += __shfl_xor(s, off);
  if (lane == 0) s_buf[idx] = s * kLinScale + modb[c];
}

// ---------------------------------------------------------------------------
// demod[b,o] = rsqrt( sum_{c,tap} (kScale*w[o,c,tap]*s[b,c])^2 + eps )
// one wave per (b,o); 1024 blocks x 4 waves
__global__ __launch_bounds__(256) void k_demod(const float* __restrict__ weight,
                                               const float* __restrict__ s_buf,
                                               float* __restrict__ demod_buf) {
  int tid = threadIdx.x, lane = tid & 63, wv = tid >> 6;
  int idx = blockIdx.x * 4 + wv; // [0,4096)
  int b = idx >> 9, o = idx & 511;
  const float* wrow = weight + (size_t)o * 4608;
  const float* srow = s_buf + b * 512;
  float ss = 0.f;
#pragma unroll
  for (int i = 0; i < 72; ++i) {
    int e = i * 64 + lane; // e = c*9 + tap
    int c = e / 9;
    float v = kScale * wrow[e] * srow[c];
    ss += v * v;
  }
#pragma unroll
  for (int off = 32; off; off >>= 1) ss += __shfl_xor(ss, off);
  if (lane == 0) demod_buf[idx] = rsqrtf(ss + 1e-8f);
}

// ---------------------------------------------------------------------------
// NCHW f32 -> NHWC bf16: in[b,c,y,x] -> in_t[b,y,x,c]
__global__ __launch_bounds__(256) void k_transpose(const float* __restrict__ in,
                                                   u16* __restrict__ in_t) {
  __shared__ u16 tile[64][66];
  int tid = threadIdx.x;
  int c0 = blockIdx.x * 64, y = blockIdx.y, b = blockIdx.z;
  const float* src = in + ((size_t)(b * 512 + c0) * 4096) + y * 64;
#pragma unroll
  for (int it = 0; it < 16; ++it) {
    int idx = it * 256 + tid;
    int cl = idx >> 6, x = idx & 63;
    tile[cl][x] = f2bf(src[(size_t)cl * 4096 + x]);
  }
  __syncthreads();
  u16* dst = in_t + ((size_t)(b * 64 + y) * 64) * 512 + c0;
#pragma unroll
  for (int it = 0; it < 16; ++it) {
    int idx = it * 256 + tid;
    int x = idx >> 6, cl = idx & 63;
    dst[(size_t)x * 512 + cl] = tile[cl][x];
  }
}

// ---------------------------------------------------------------------------
// Build w_t fragment tiles. Block = (ct, ot, b). LDS: 9 tap-tiles of 512 u16,
// then coalesced u32 write-out. Fragment pos = (m + 16*(k>>3))*8 + (k&7).
__global__ __launch_bounds__(256) void k_weights(const float* __restrict__ weight,
                                                 const float* __restrict__ s_buf,
                                                 const float* __restrict__ demod_buf,
                                                 u16* __restrict__ w_t) {
  __shared__ u16 tiles[9][512];
  int tid = threadIdx.x;
  int ct = blockIdx.x, ot = blockIdx.y, b = blockIdx.z;
#pragma unroll
  for (int j = 0; j < 2; ++j) {
    int pi = tid * 2 + j;       // [0,512)
    int m = pi & 15, kk = pi >> 4;
    int o = ot * 16 + m, c = ct * 32 + kk;
    float sd = s_buf[b * 512 + c] * kScale;
    float dm = demod_buf[b * 512 + o];
    const float* wp = weight + ((size_t)o * 512 + c) * 9;
    int pos = ((m + ((kk >> 3) << 4)) << 3) + (kk & 7);
#pragma unroll
    for (int tap = 0; tap < 9; ++tap)
      tiles[tap][pos] = f2bf(wp[tap] * sd * dm);
  }
  __syncthreads();
  const unsigned* tl = (const unsigned*)tiles;
  unsigned* wt32 = (unsigned*)w_t;
#pragma unroll
  for (int tap = 0; tap < 9; ++tap)
    wt32[(size_t)(((b * 9 + tap) * 16 + ct) * 32 + ot) * 256 + tid] = tl[tap * 256 + tid];
}

// ---------------------------------------------------------------------------
// Implicit-GEMM conv. Grid (nt=32, mt=4, b=8). 128 O x 128 pixels (2 rows).
__global__ __launch_bounds__(256) void k_conv(const u16* __restrict__ in_t,
                                              const u16* __restrict__ w_t,
                                              float* __restrict__ out) {
  __shared__ char smem[40960]; // A: [0,24576) = 3 taps x 8KB ; B: [24576,40960)
  char* As = smem;
  char* Bs = smem + 24576;
  const int tid = threadIdx.x;
  const int lane = tid & 63;
  const int wv = tid >> 6;
  const int wm = wv >> 1, wn = wv & 1;
  const int quad = lane >> 4, m16 = lane & 15;
  const int nt = blockIdx.x, mt = blockIdx.y, b = blockIdx.z;
  const int y0 = nt * 2;

  floatx4 acc[4][4];
#pragma unroll
  for (int i = 0; i < 4; ++i)
#pragma unroll
    for (int j = 0; j < 4; ++j) acc[i][j] = (floatx4){0.f, 0.f, 0.f, 0.f};

  for (int ct = 0; ct < 16; ++ct) {
    const int c0 = ct * 32;
    // stage B: rows y0-1..y0+2, 64 x, 32 ch; chunk q at byte s*64+((q^(x&3))*16)
#pragma unroll
    for (int r = 0; r < 4; ++r) {
      const int ci = r * 256 + tid;
      const int s = ci >> 2, qi = ci & 3;
      const int x = s & 63;
      const int y = y0 - 1 + r; // block-uniform
      const int qd = qi ^ (x & 3);
      char* lbase = Bs + (r * 4 + wv) * 1024;
      if ((unsigned)y < 64u) {
        const u16* g = in_t + (((size_t)(b * 64 + y) * 64 + x) * 512 + c0 + qd * 8);
        GLD16(g, lbase);
      } else {
        *(uint4*)(Bs + ci * 16) = make_uint4(0u, 0u, 0u, 0u);
      }
    }
    for (int dy = 0; dy < 3; ++dy) {
      // stage A: taps dy*3+{0,1,2}
#pragma unroll
      for (int r6 = 0; r6 < 6; ++r6) {
        const int sec = r6 >> 1, half = r6 & 1;
        const int tap = dy * 3 + sec;
        const u16* g = w_t + ((size_t)((b * 9 + tap) * 16 + ct) << 14) +
                       mt * 4096 + half * 2048 + wv * 512 + lane * 8;
        char* lbase = As + sec * 8192 + half * 4096 + wv * 1024;
        GLD16(g, lbase);
      }
      __syncthreads();
#pragma unroll
      for (int dx = 0; dx < 3; ++dx) {
        bf16x8 af[4];
#pragma unroll
        for (int ms = 0; ms < 4; ++ms)
          af[ms] = *(const bf16x8*)(As + dx * 8192 + (wm * 4 + ms) * 1024 + lane * 16);
#pragma unroll
        for (int ns = 0; ns < 4; ++ns) {
          const int nl = wn * 64 + ns * 16 + m16;
          const int ly = nl >> 6, lx = nl & 63;
          const int sx = lx + dx - 1;
          bf16x8 bv;
          if ((unsigned)sx < 64u) {
            const int s = (ly + dy) * 64 + sx;
            bv = *(const bf16x8*)(Bs + s * 64 + ((quad ^ (sx & 3)) << 4));
          } else {
#pragma unroll
            for (int j = 0; j < 8; ++j) bv[j] = (bf16_t)0.f;
          }
#pragma unroll
          for (int ms = 0; ms < 4; ++ms)
            acc[ms][ns] =
                __builtin_amdgcn_mfma_f32_16x16x32_bf16(af[ms], bv, acc[ms][ns], 0, 0, 0);
        }
      }
      __syncthreads();
    }
  }
  // epilogue: D[m=quad*4+r][n=lane&15], f32 out
  const int ob = mt * 128 + wm * 64;
  const int nb = nt * 128 + wn * 64;
#pragma unroll
  for (int ms = 0; ms < 4; ++ms)
#pragma unroll
    for (int ns = 0; ns < 4; ++ns) {
      const int n = nb + ns * 16 + m16;
#pragma unroll
      for (int r = 0; r < 4; ++r) {
        const int o = ob + ms * 16 + quad * 4 + r;
        out[((size_t)(b * 512 + o) << 12) + n] = acc[ms][ns][r];
      }
    }
}

// ---------------------------------------------------------------------------
extern "C" void kernel_launch(void* const* d_in, const int* in_sizes, int n_in,
                              void* d_out, int out_size, void* d_ws, size_t ws_size,
                              hipStream_t stream) {
  const float* input = (const float*)d_in[0];   // [8,512,64,64] f32
  const float* style = (const float*)d_in[1];   // [8,512] f32
  const float* weight = (const float*)d_in[2];  // [1,512,512,3,3] f32
  const float* modw = (const float*)d_in[3];    // [512,512] f32
  const float* modb = (const float*)d_in[4];    // [512] f32
  float* out = (float*)d_out;                   // [8,512,64,64] f32
  char* ws = (char*)d_ws;
  float* s_buf = (float*)ws;                        // 16 KB
  float* demod_buf = (float*)(ws + 16384);          // 16 KB
  u16* in_t = (u16*)(ws + 32768);                   // NHWC bf16, 33,554,432 B
  u16* w_t = (u16*)(ws + 32768 + 33554432);         // frag bf16, 37,748,736 B

  k_style<<<dim3(1024), dim3(256), 0, stream>>>(style, modw, modb, s_buf);
  k_demod<<<dim3(1024), dim3(256), 0, stream>>>(weight, s_buf, demod_buf);
  k_transpose<<<dim3(8, 64, 8), dim3(256), 0, stream>>>(input, in_t);
  k_weights<<<dim3(16, 32, 8), dim3(256), 0, stream>>>(weight, s_buf, demod_buf, w_t);
  k_conv<<<dim3(32, 4, 8), dim3(256), 0, stream>>>(in_t, w_t, out);
}